// Round 14
// baseline (205.848 us; speedup 1.0000x reference)
//
#include <hip/hip_runtime.h>

#define KK 4
#define BATCH 32768
#define NN 10
#define GPW 6            // graphs per wave (10 lanes each, 60 of 64 lanes)
#define SLAB 132         // dwords per graph slab; 132 % 32 = 4 -> conflict-free mac broadcasts
#define NTHREADS 256     // 4 waves; wave w == k index

static constexpr size_t OFF_AIK = (size_t)KK * BATCH * NN * NN;           // 13107200
static constexpr size_t OFF_TJ  = OFF_AIK + (size_t)KK * BATCH * NN;      // 14417920
static constexpr size_t OFF_R   = OFF_TJ  + (size_t)KK * BATCH * NN;      // 15728640
static constexpr size_t OFF_RT  = OFF_R   + (size_t)KK * BATCH * NN * NN; // 28835840

#define WSYNC() do { asm volatile("" ::: "memory"); \
                     __builtin_amdgcn_wave_barrier(); \
                     asm volatile("" ::: "memory"); } while (0)

__device__ __forceinline__ float rcpf(float x) {
#if __has_builtin(__builtin_amdgcn_rcpf)
    return __builtin_amdgcn_rcpf(x);
#else
    return 1.f / x;
#endif
}
__device__ __forceinline__ float fexp2(float x) {
#if __has_builtin(__builtin_amdgcn_exp2f)
    return __builtin_amdgcn_exp2f(x);
#else
    return exp2f(x);
#endif
}

// ---- packed fp32 helpers (VOP3P; add/mul/fma only on gfx950). Bit-exact IEEE fp32.
//      ALL-VGPR forms: weights are vector-loaded (vmcnt path), not SGPR (lgkmcnt/SMEM). ----
static __device__ __forceinline__ float2 pk_mul2(float2 a, float2 b) {
    float2 d; asm("v_pk_mul_f32 %0, %1, %2" : "=v"(d) : "v"(a), "v"(b)); return d; }
static __device__ __forceinline__ float2 pk_add2(float2 a, float2 b) {
    float2 d; asm("v_pk_add_f32 %0, %1, %2" : "=v"(d) : "v"(a), "v"(b)); return d; }
static __device__ __forceinline__ float2 pk_fma2(float2 a, float2 b, float2 c) {
    float2 d; asm("v_pk_fma_f32 %0, %1, %2, %3" : "=v"(d) : "v"(a), "v"(b), "v"(c)); return d; }
// broadcast src0.lo (or .hi) across both result halves
static __device__ __forceinline__ float2 pk_fma_blo(float2 a, float2 b, float2 c) {
    float2 d; asm("v_pk_fma_f32 %0, %1, %2, %3 op_sel_hi:[0,1,1]"
                  : "=v"(d) : "v"(a), "v"(b), "v"(c)); return d; }
static __device__ __forceinline__ float2 pk_fma_bhi(float2 a, float2 b, float2 c) {
    float2 d; asm("v_pk_fma_f32 %0, %1, %2, %3 op_sel:[1,0,0] op_sel_hi:[1,1,1]"
                  : "=v"(d) : "v"(a), "v"(b), "v"(c)); return d; }
static __device__ __forceinline__ float2 pk_mul_blo(float2 a, float2 b) {
    float2 d; asm("v_pk_mul_f32 %0, %1, %2 op_sel_hi:[0,1]"
                  : "=v"(d) : "v"(a), "v"(b)); return d; }
static __device__ __forceinline__ float2 leaky2(float2 v) {
    return make_float2(fmaxf(v.x, 0.f) + 0.01f * fminf(v.x, 0.f),
                       fmaxf(v.y, 0.f) + 0.01f * fminf(v.y, 0.f)); }

__global__ __launch_bounds__(NTHREADS, 8)
void gnn_fused(const float* __restrict__ xin,
               const float* __restrict__ ew,
               const float* __restrict__ eigen,
               const float* __restrict__ a0p,
               const float* __restrict__ W0p,
               const float* __restrict__ b0p,
               const float* __restrict__ W1p,
               const float* __restrict__ b1p,
               const float* __restrict__ bpp,
               const float* __restrict__ cpp,
               const float* __restrict__ wwp,
               float* __restrict__ out)
{
    __shared__ __align__(16) float sm[KK * GPW * SLAB];   // 12,672 B

    const float LOG2E = 1.4426950408889634f;
    const float2 zero2 = make_float2(0.f, 0.f);

    // opaque zero in a VGPR: forces weight loads onto the VECTOR memory path
    // (global_load_dwordx2, vmcnt) instead of s_load (SMEM, shared lgkmcnt with DS).
    int zf;
    asm volatile("v_mov_b32 %0, 0" : "=v"(zf));

    const int t = threadIdx.x;
    const int l = t & 63;
    const int w = t >> 6;             // k index
    int s = l / 10;                   // graph in wave 0..6
    const int n = l % 10;             // node
    const bool dup = (s >= GPW);
    if (dup) s = GPW - 1;
    const int bb  = blockIdx.x * GPW + s;
    const bool valid = (!dup) && (bb < BATCH);
    const int bbc = (bb < BATCH) ? bb : (BATCH - 1);
    const int g   = w * BATCH + bbc;

    float* slab = sm + (w * GPW + s) * SLAB;

    // ---- own outgoing edge-weight row DIRECT from global ----
    float rowv[9];
    {
        const float* rp = ew + (size_t)g * 90 + n * 9;
#pragma unroll
        for (int c = 0; c < 9; ++c) rowv[c] = rp[c];
    }
    const size_t node = (size_t)g * NN + n;
    const float x0 = xin[node * 3 + 0];
    const float x1 = xin[node * 3 + 1];
    const float x2 = xin[node * 3 + 2];
    const float eig = eigen[g];
    const float a0v = a0p[0];

    float wout[10];
    wout[0] = (n == 0) ? 0.f : rowv[0];
    wout[9] = (n == 9) ? 0.f : rowv[8];
#pragma unroll
    for (int j = 1; j < 9; ++j)
        wout[j] = (j == n) ? 0.f : ((j < n) ? rowv[j] : rowv[j - 1]);

    // ---- R (row n = outgoing) ----
    if (valid) {
        float* pr = out + OFF_R + (size_t)g * 100 + n * 10;
#pragma unroll
        for (int q = 0; q < 5; ++q)
            ((float2*)pr)[q] = make_float2(wout[2*q] * eig, wout[2*q+1] * eig);
    }

    // ---- transpose through LDS: wt[j][n] = w(n->j) ----
#pragma unroll
    for (int j = 0; j < 10; ++j) slab[j * 10 + n] = wout[j];
    WSYNC();
    float2 win2[5];
    {
        const float* rp = slab + n * 10;
#pragma unroll
        for (int q = 0; q < 5; ++q) win2[q] = *(const float2*)(rp + 2 * q);
    }
    const float deg = (win2[0].x + win2[0].y) + (win2[1].x + win2[1].y)
                    + (win2[2].x + win2[2].y) + (win2[3].x + win2[3].y)
                    + (win2[4].x + win2[4].y);

    // ---- R_t (row n = incoming) ----
    if (valid) {
        float* pt = out + OFF_RT + (size_t)g * 100 + n * 10;
#pragma unroll
        for (int q = 0; q < 5; ++q)
            ((float2*)pt)[q] = make_float2(win2[q].x * eig, win2[q].y * eig);
    }

    // ---- dinv exchange ----
    const float dv = (deg > 0.f) ? __frsqrt_rn(deg) : 0.f;
    slab[120 + n] = dv;
    WSYNC();
    float2 dinv2[5];
#pragma unroll
    for (int q = 0; q < 5; ++q) dinv2[q] = *(const float2*)(slab + 120 + 2 * q);
    const float2 dv2 = make_float2(dv, dv);
    float2 arow2[5];
#pragma unroll
    for (int q = 0; q < 5; ++q)
        arow2[q] = pk_mul2(pk_mul2(dinv2[q], win2[q]), dv2);

    // vector-path weight access (vaddr = zf + imm; wave-uniform -> 1 L2 txn, broadcast)
#define LW2(P, OFF) (*(const float2*)((P) + zf + (OFF)))

    // ================= TAGConv layer 0: 3 -> 16, packed =================
    const float2 x01 = make_float2(x0, x1);
    const float2 x2p = make_float2(x2, 0.f);
    float2 acc0p[8];
#pragma unroll
    for (int q = 0; q < 8; ++q) {
        float2 wa = LW2(W0p, 2*q);
        float2 wb = LW2(W0p, 16 + 2*q);
        float2 wc = LW2(W0p, 32 + 2*q);
        acc0p[q] = pk_mul_blo(x01, wa);
        acc0p[q] = pk_fma_bhi(x01, wb, acc0p[q]);
        acc0p[q] = pk_fma_blo(x2p, wc, acc0p[q]);
    }
    {
        float2 hab = x01, hcj = x2p;
#pragma unroll
        for (int hop = 1; hop <= 3; ++hop) {
            *(float4*)(slab + n * 12) = make_float4(hab.x, hab.y, hcj.x, hcj.y);
            WSYNC();
            float2 nab = zero2, ncj = zero2;
#pragma unroll
            for (int m = 0; m < 10; ++m) {
                const float4 hm = *(const float4*)(slab + m * 12);
                const float2 hx = make_float2(hm.x, hm.y);
                const float2 hz = make_float2(hm.z, hm.w);
                const float2 am = arow2[m >> 1];
                if ((m & 1) == 0) {
                    nab = pk_fma_blo(am, hx, nab);
                    ncj = pk_fma_blo(am, hz, ncj);
                } else {
                    nab = pk_fma_bhi(am, hx, nab);
                    ncj = pk_fma_bhi(am, hz, ncj);
                }
            }
            WSYNC();
            __builtin_amdgcn_s_setprio(1);
#pragma unroll
            for (int q = 0; q < 8; ++q) {
                float2 wa = LW2(W0p, hop*48 + 2*q);
                float2 wb = LW2(W0p, hop*48 + 16 + 2*q);
                float2 wc = LW2(W0p, hop*48 + 32 + 2*q);
                acc0p[q] = pk_fma_blo(nab, wa, acc0p[q]);
                acc0p[q] = pk_fma_bhi(nab, wb, acc0p[q]);
                acc0p[q] = pk_fma_blo(ncj, wc, acc0p[q]);
            }
            __builtin_amdgcn_s_setprio(0);
            hab = nab; hcj = ncj;
        }
    }
    float2 y1p[8];
#pragma unroll
    for (int q = 0; q < 8; ++q) {
        float2 b2 = LW2(b0p, 2*q);
        y1p[q] = leaky2(pk_add2(acc0p[q], b2));
    }

    // ===== TAGConv layer 1: 16 -> 8, Horner, packed: out = z0+A(z1+A(z2+A z3)) =====
    float2 cur2[4];
    __builtin_amdgcn_s_setprio(1);
#pragma unroll
    for (int q = 0; q < 4; ++q) {
        float2 w0 = LW2(W1p, 384 + 2*q);
        cur2[q] = pk_mul_blo(y1p[0], w0);
        float2 w1 = LW2(W1p, 384 + 8 + 2*q);
        cur2[q] = pk_fma_bhi(y1p[0], w1, cur2[q]);
#pragma unroll
        for (int p8 = 1; p8 < 8; ++p8) {
            float2 wl = LW2(W1p, 384 + (2*p8)*8 + 2*q);
            float2 wh = LW2(W1p, 384 + (2*p8+1)*8 + 2*q);
            cur2[q] = pk_fma_blo(y1p[p8], wl, cur2[q]);
            cur2[q] = pk_fma_bhi(y1p[p8], wh, cur2[q]);
        }
    }
    __builtin_amdgcn_s_setprio(0);
#pragma unroll
    for (int kh = 2; kh >= 0; --kh) {
        *(float4*)(slab + n * 12)     = make_float4(cur2[0].x, cur2[0].y, cur2[1].x, cur2[1].y);
        *(float4*)(slab + n * 12 + 4) = make_float4(cur2[2].x, cur2[2].y, cur2[3].x, cur2[3].y);
        WSYNC();
        float2 ag[4] = {zero2, zero2, zero2, zero2};
#pragma unroll
        for (int m = 0; m < 10; ++m) {
            const float4 p = *(const float4*)(slab + m * 12);
            const float4 r = *(const float4*)(slab + m * 12 + 4);
            const float2 pa = make_float2(p.x, p.y), pb = make_float2(p.z, p.w);
            const float2 ra = make_float2(r.x, r.y), rb = make_float2(r.z, r.w);
            const float2 am = arow2[m >> 1];
            if ((m & 1) == 0) {
                ag[0] = pk_fma_blo(am, pa, ag[0]);
                ag[1] = pk_fma_blo(am, pb, ag[1]);
                ag[2] = pk_fma_blo(am, ra, ag[2]);
                ag[3] = pk_fma_blo(am, rb, ag[3]);
            } else {
                ag[0] = pk_fma_bhi(am, pa, ag[0]);
                ag[1] = pk_fma_bhi(am, pb, ag[1]);
                ag[2] = pk_fma_bhi(am, ra, ag[2]);
                ag[3] = pk_fma_bhi(am, rb, ag[3]);
            }
        }
        WSYNC();
        __builtin_amdgcn_s_setprio(1);
#pragma unroll
        for (int q = 0; q < 4; ++q) {
            cur2[q] = ag[q];
#pragma unroll
            for (int p8 = 0; p8 < 8; ++p8) {
                float2 wl = LW2(W1p, kh*128 + (2*p8)*8 + 2*q);
                float2 wh = LW2(W1p, kh*128 + (2*p8+1)*8 + 2*q);
                cur2[q] = pk_fma_blo(y1p[p8], wl, cur2[q]);
                cur2[q] = pk_fma_bhi(y1p[p8], wh, cur2[q]);
            }
        }
        __builtin_amdgcn_s_setprio(0);
    }
    float2 y2p[4];
#pragma unroll
    for (int q = 0; q < 4; ++q) {
        float2 b2 = LW2(b1p, 2*q);
        y2p[q] = leaky2(pk_add2(cur2[q], b2));
    }

    // ================= heads =================
    *(float4*)(slab + n * 12)     = make_float4(y2p[0].x, y2p[0].y, y2p[1].x, y2p[1].y);
    *(float4*)(slab + n * 12 + 4) = make_float4(y2p[2].x, y2p[2].y, y2p[3].x, y2p[3].y);

    float2 accA = zero2, accT = zero2;
#pragma unroll
    for (int q = 0; q < 4; ++q) {
        float2 bp2 = LW2(bpp, 2*q);
        float2 cp2 = LW2(cpp, 2*q);
        accA = pk_fma2(y2p[q], bp2, accA);
        accT = pk_fma2(y2p[q], cp2, accT);
    }
    const float ay = accA.x + accA.y;
    const float ty = accT.x + accT.y;
    if (valid)
        out[OFF_AIK + (size_t)g * 10 + n] = a0v + fmaxf(ay, 0.f);

    float tk = ty * (1.f - fmaxf(x2, 0.f));
    if (tk == 0.f) tk = -1e10f;
    const float tks = tk * LOG2E;     // exp2-scaled logit (stays live in reg)

    float2 yw2[4];
#pragma unroll
    for (int qd = 0; qd < 4; ++qd) {
        float2 aA = zero2, aB = zero2;
#pragma unroll
        for (int q = 0; q < 4; ++q) {
            float2 wA = LW2(wwp, (2*qd)*8 + 2*q);
            float2 wB = LW2(wwp, (2*qd+1)*8 + 2*q);
            aA = pk_fma2(y2p[q], wA, aA);
            aB = pk_fma2(y2p[q], wB, aB);
        }
        yw2[qd] = make_float2(aA.x + aA.y, aB.x + aB.y);
    }
    WSYNC();   // y2 rows visible
    float kyr[10];   // exp2-scaled logits; stay live across the barrier
#pragma unroll
    for (int m = 0; m < 10; ++m) {
        const float4 p = *(const float4*)(slab + m * 12);
        const float4 r = *(const float4*)(slab + m * 12 + 4);
        float2 acc = pk_mul2(yw2[0], make_float2(p.x, p.y));
        acc = pk_fma2(yw2[1], make_float2(p.z, p.w), acc);
        acc = pk_fma2(yw2[2], make_float2(r.x, r.y), acc);
        acc = pk_fma2(yw2[3], make_float2(r.z, r.w), acc);
        kyr[m] = (acc.x + acc.y) * LOG2E;
    }
    WSYNC();   // all y2 reads done; rows reusable for ky (stride 12, b128-packed)
    *(float4*)(slab + n * 12)     = make_float4(kyr[0], kyr[1], kyr[2], kyr[3]);
    *(float4*)(slab + n * 12 + 4) = make_float4(kyr[4], kyr[5], kyr[6], kyr[7]);
    *(float2*)(slab + n * 12 + 8) = make_float2(kyr[8], kyr[9]);
    slab[120 + n] = tks;

    __syncthreads();   // the ONE cross-wave barrier

    const int ko0 = (w + 1) & 3, ko1 = (w + 2) & 3, ko2 = (w + 3) & 3;

    // ---- t softmax over K: own logit from reg, 3 other-slab reads ----
    {
        const float u0 = sm[(ko0*GPW + s)*SLAB + 120 + n];
        const float u1 = sm[(ko1*GPW + s)*SLAB + 120 + n];
        const float u2 = sm[(ko2*GPW + s)*SLAB + 120 + n];
        const float mx = fmaxf(fmaxf(tks, u0), fmaxf(u1, u2));
        const float eo = fexp2(tks - mx);
        const float den = eo + fexp2(u0 - mx) + fexp2(u1 - mx) + fexp2(u2 - mx);
        if (valid)
            out[OFF_TJ + (size_t)g * 10 + n] = eo * rcpf(den);
    }
    // ---- k_ij softmax over K: own row from kyr regs, 3 other slabs x 3 reads ----
    {
        const float* sA = sm + (ko0*GPW + s)*SLAB + n * 12;
        const float* sB = sm + (ko1*GPW + s)*SLAB + n * 12;
        const float* sC = sm + (ko2*GPW + s)*SLAB + n * 12;
        const float4 a0 = *(const float4*)(sA);
        const float4 a1 = *(const float4*)(sA + 4);
        const float2 a2 = *(const float2*)(sA + 8);
        const float4 b0 = *(const float4*)(sB);
        const float4 b1 = *(const float4*)(sB + 4);
        const float2 b2 = *(const float2*)(sB + 8);
        const float4 c0 = *(const float4*)(sC);
        const float4 c1 = *(const float4*)(sC + 4);
        const float2 c2 = *(const float2*)(sC + 8);
        float va[10], vb[10], vc[10];
        va[0]=a0.x; va[1]=a0.y; va[2]=a0.z; va[3]=a0.w;
        va[4]=a1.x; va[5]=a1.y; va[6]=a1.z; va[7]=a1.w; va[8]=a2.x; va[9]=a2.y;
        vb[0]=b0.x; vb[1]=b0.y; vb[2]=b0.z; vb[3]=b0.w;
        vb[4]=b1.x; vb[5]=b1.y; vb[6]=b1.z; vb[7]=b1.w; vb[8]=b2.x; vb[9]=b2.y;
        vc[0]=c0.x; vc[1]=c0.y; vc[2]=c0.z; vc[3]=c0.w;
        vc[4]=c1.x; vc[5]=c1.y; vc[6]=c1.z; vc[7]=c1.w; vc[8]=c2.x; vc[9]=c2.y;
        float o[10];
#pragma unroll
        for (int m = 0; m < 10; ++m) {
            const float mx = fmaxf(fmaxf(kyr[m], va[m]), fmaxf(vb[m], vc[m]));
            const float eo = fexp2(kyr[m] - mx);
            const float den = eo + fexp2(va[m] - mx) + fexp2(vb[m] - mx) + fexp2(vc[m] - mx);
            o[m] = eo * rcpf(den);
        }
        if (valid) {
            float* po = out + (size_t)g * 100 + n * 10;
#pragma unroll
            for (int q = 0; q < 5; ++q)
                ((float2*)po)[q] = make_float2(o[2*q], o[2*q+1]);
        }
    }
#undef LW2
}

extern "C" void kernel_launch(void* const* d_in, const int* in_sizes, int n_in,
                              void* d_out, int out_size, void* d_ws, size_t ws_size,
                              hipStream_t stream) {
    const float* x   = (const float*)d_in[0];
    // d_in[1] = edge_index: deterministic pattern, never read
    const float* ew  = (const float*)d_in[2];
    const float* eig = (const float*)d_in[6];
    const float* a0  = (const float*)d_in[7];
    const float* W0  = (const float*)d_in[8];
    const float* b0  = (const float*)d_in[9];
    const float* W1  = (const float*)d_in[10];
    const float* b1  = (const float*)d_in[11];
    const float* bpw = (const float*)d_in[12];
    const float* cpw = (const float*)d_in[13];
    const float* www = (const float*)d_in[14];
    float* out = (float*)d_out;

    const int grid = (BATCH + GPW - 1) / GPW;   // 5462
    gnn_fused<<<dim3(grid), dim3(NTHREADS), 0, stream>>>(
        x, ew, eig, a0, W0, b0, W1, b1, bpw, cpw, www, out);
}

// Round 15
// 74.929 us; speedup vs baseline: 2.7472x; 2.7472x over previous
//
#include <hip/hip_runtime.h>

#define KK 4
#define BATCH 32768
#define NN 10
#define GPW 6            // graphs per wave (10 lanes each, 60 of 64 lanes)
#define SLAB 132         // dwords per graph slab; 132 % 32 = 4 -> conflict-free mac broadcasts
#define NTHREADS 256     // 4 waves; wave w == k index

static constexpr size_t OFF_AIK = (size_t)KK * BATCH * NN * NN;           // 13107200
static constexpr size_t OFF_TJ  = OFF_AIK + (size_t)KK * BATCH * NN;      // 14417920
static constexpr size_t OFF_R   = OFF_TJ  + (size_t)KK * BATCH * NN;      // 15728640
static constexpr size_t OFF_RT  = OFF_R   + (size_t)KK * BATCH * NN * NN; // 28835840

#define WSYNC() do { asm volatile("" ::: "memory"); \
                     __builtin_amdgcn_wave_barrier(); \
                     asm volatile("" ::: "memory"); } while (0)

__device__ __forceinline__ float rcpf(float x) {
#if __has_builtin(__builtin_amdgcn_rcpf)
    return __builtin_amdgcn_rcpf(x);
#else
    return 1.f / x;
#endif
}
__device__ __forceinline__ float fexp2(float x) {
#if __has_builtin(__builtin_amdgcn_exp2f)
    return __builtin_amdgcn_exp2f(x);
#else
    return exp2f(x);
#endif
}

// ---- packed fp32 helpers (VOP3P; add/mul/fma only on gfx950). Bit-exact IEEE fp32. ----
static __device__ __forceinline__ float2 pk_mul2(float2 a, float2 b) {
    float2 d; asm("v_pk_mul_f32 %0, %1, %2" : "=v"(d) : "v"(a), "v"(b)); return d; }
static __device__ __forceinline__ float2 pk_fma2(float2 a, float2 b, float2 c) {
    float2 d; asm("v_pk_fma_f32 %0, %1, %2, %3" : "=v"(d) : "v"(a), "v"(b), "v"(c)); return d; }
// broadcast src0.lo (or .hi) across both result halves
static __device__ __forceinline__ float2 pk_fma_blo(float2 a, float2 b, float2 c) {
    float2 d; asm("v_pk_fma_f32 %0, %1, %2, %3 op_sel_hi:[0,1,1]"
                  : "=v"(d) : "v"(a), "v"(b), "v"(c)); return d; }
static __device__ __forceinline__ float2 pk_fma_bhi(float2 a, float2 b, float2 c) {
    float2 d; asm("v_pk_fma_f32 %0, %1, %2, %3 op_sel:[1,0,0] op_sel_hi:[1,1,1]"
                  : "=v"(d) : "v"(a), "v"(b), "v"(c)); return d; }
// same, with wave-uniform weight pair held in SGPRs (src1)
static __device__ __forceinline__ float2 pk_fma_blo_s(float2 a, float2 bs, float2 c) {
    float2 d; asm("v_pk_fma_f32 %0, %1, %2, %3 op_sel_hi:[0,1,1]"
                  : "=v"(d) : "v"(a), "s"(bs), "v"(c)); return d; }
static __device__ __forceinline__ float2 pk_fma_bhi_s(float2 a, float2 bs, float2 c) {
    float2 d; asm("v_pk_fma_f32 %0, %1, %2, %3 op_sel:[1,0,0] op_sel_hi:[1,1,1]"
                  : "=v"(d) : "v"(a), "s"(bs), "v"(c)); return d; }
static __device__ __forceinline__ float2 pk_mul_blo_s(float2 a, float2 bs) {
    float2 d; asm("v_pk_mul_f32 %0, %1, %2 op_sel_hi:[0,1]"
                  : "=v"(d) : "v"(a), "s"(bs)); return d; }
static __device__ __forceinline__ float2 pk_fma_vs(float2 a, float2 bs, float2 c) {
    float2 d; asm("v_pk_fma_f32 %0, %1, %2, %3" : "=v"(d) : "v"(a), "s"(bs), "v"(c)); return d; }
static __device__ __forceinline__ float2 pk_add_vs(float2 a, float2 bs) {
    float2 d; asm("v_pk_add_f32 %0, %1, %2" : "=v"(d) : "v"(a), "s"(bs)); return d; }
static __device__ __forceinline__ float2 leaky2(float2 v) {
    return make_float2(fmaxf(v.x, 0.f) + 0.01f * fminf(v.x, 0.f),
                       fmaxf(v.y, 0.f) + 0.01f * fminf(v.y, 0.f)); }

__global__ __launch_bounds__(NTHREADS, 8)
void gnn_fused(const float* __restrict__ xin,
               const float* __restrict__ ew,
               const float* __restrict__ eigen,
               const float* __restrict__ a0p,
               const float* __restrict__ W0p,
               const float* __restrict__ b0p,
               const float* __restrict__ W1p,
               const float* __restrict__ b1p,
               const float* __restrict__ bpp,
               const float* __restrict__ cpp,
               const float* __restrict__ wwp,
               float* __restrict__ out)
{
    __shared__ __align__(16) float sm[KK * GPW * SLAB];   // 12,672 B

    const float LOG2E = 1.4426950408889634f;

    const int t = threadIdx.x;
    const int l = t & 63;
    const int w = t >> 6;             // k index
    int s = l / 10;                   // graph in wave 0..6
    const int n = l % 10;             // node
    const bool dup = (s >= GPW);
    if (dup) s = GPW - 1;
    const int bb  = blockIdx.x * GPW + s;
    const bool valid = (!dup) && (bb < BATCH);
    const int bbc = (bb < BATCH) ? bb : (BATCH - 1);
    const int g   = w * BATCH + bbc;

    float* slab = sm + (w * GPW + s) * SLAB;

    // ---- own outgoing edge-weight row DIRECT from global ----
    float rowv[9];
    {
        const float* rp = ew + (size_t)g * 90 + n * 9;
#pragma unroll
        for (int c = 0; c < 9; ++c) rowv[c] = rp[c];
    }
    const size_t node = (size_t)g * NN + n;
    const float x0 = xin[node * 3 + 0];
    const float x1 = xin[node * 3 + 1];
    const float x2 = xin[node * 3 + 2];
    const float eig = eigen[g];
    const float a0v = a0p[0];

    float wout[10];
    wout[0] = (n == 0) ? 0.f : rowv[0];
    wout[9] = (n == 9) ? 0.f : rowv[8];
#pragma unroll
    for (int j = 1; j < 9; ++j)
        wout[j] = (j == n) ? 0.f : ((j < n) ? rowv[j] : rowv[j - 1]);

    // ---- R (row n = outgoing) ----
    if (valid) {
        float* pr = out + OFF_R + (size_t)g * 100 + n * 10;
#pragma unroll
        for (int q = 0; q < 5; ++q)
            ((float2*)pr)[q] = make_float2(wout[2*q] * eig, wout[2*q+1] * eig);
    }

    // ---- transpose through LDS: wt[j][n] = w(n->j) ----
#pragma unroll
    for (int j = 0; j < 10; ++j) slab[j * 10 + n] = wout[j];
    WSYNC();
    float2 win2[5];
    {
        const float* rp = slab + n * 10;
#pragma unroll
        for (int q = 0; q < 5; ++q) win2[q] = *(const float2*)(rp + 2 * q);
    }
    const float deg = (win2[0].x + win2[0].y) + (win2[1].x + win2[1].y)
                    + (win2[2].x + win2[2].y) + (win2[3].x + win2[3].y)
                    + (win2[4].x + win2[4].y);

    // ---- R_t (row n = incoming) ----
    if (valid) {
        float* pt = out + OFF_RT + (size_t)g * 100 + n * 10;
#pragma unroll
        for (int q = 0; q < 5; ++q)
            ((float2*)pt)[q] = make_float2(win2[q].x * eig, win2[q].y * eig);
    }

    // ---- dinv exchange ----
    const float dv = (deg > 0.f) ? __frsqrt_rn(deg) : 0.f;
    slab[120 + n] = dv;
    WSYNC();
    float2 dinv2[5];
#pragma unroll
    for (int q = 0; q < 5; ++q) dinv2[q] = *(const float2*)(slab + 120 + 2 * q);
    const float2 dv2 = make_float2(dv, dv);
    float2 arow2[5];
#pragma unroll
    for (int q = 0; q < 5; ++q)
        arow2[q] = pk_mul2(pk_mul2(dinv2[q], win2[q]), dv2);

    // ================= TAGConv layer 0: 3 -> 16, packed =================
    const float2 x01 = make_float2(x0, x1);
    const float2 x2p = make_float2(x2, 0.f);
    float2 acc0p[8];
#pragma unroll
    for (int q = 0; q < 8; ++q) {
        float2 wa = *(const float2*)(W0p + 2*q);
        float2 wb = *(const float2*)(W0p + 16 + 2*q);
        float2 wc = *(const float2*)(W0p + 32 + 2*q);
        acc0p[q] = pk_mul_blo_s(x01, wa);
        acc0p[q] = pk_fma_bhi_s(x01, wb, acc0p[q]);
        acc0p[q] = pk_fma_blo_s(x2p, wc, acc0p[q]);
    }
    {
        float2 hab = x01, hcj = x2p;
#pragma unroll
        for (int hop = 1; hop <= 3; ++hop) {
            *(float4*)(slab + n * 12) = make_float4(hab.x, hab.y, hcj.x, hcj.y);
            WSYNC();
            float2 nab = make_float2(0.f, 0.f), ncj = make_float2(0.f, 0.f);
#pragma unroll
            for (int m = 0; m < 10; ++m) {
                const float4 hm = *(const float4*)(slab + m * 12);
                const float2 hx = make_float2(hm.x, hm.y);
                const float2 hz = make_float2(hm.z, hm.w);
                const float2 am = arow2[m >> 1];
                if ((m & 1) == 0) {
                    nab = pk_fma_blo(am, hx, nab);
                    ncj = pk_fma_blo(am, hz, ncj);
                } else {
                    nab = pk_fma_bhi(am, hx, nab);
                    ncj = pk_fma_bhi(am, hz, ncj);
                }
            }
            WSYNC();
            __builtin_amdgcn_s_setprio(1);
#pragma unroll
            for (int q = 0; q < 8; ++q) {
                float2 wa = *(const float2*)(W0p + hop*48 + 2*q);
                float2 wb = *(const float2*)(W0p + hop*48 + 16 + 2*q);
                float2 wc = *(const float2*)(W0p + hop*48 + 32 + 2*q);
                acc0p[q] = pk_fma_blo_s(nab, wa, acc0p[q]);
                acc0p[q] = pk_fma_bhi_s(nab, wb, acc0p[q]);
                acc0p[q] = pk_fma_blo_s(ncj, wc, acc0p[q]);
            }
            __builtin_amdgcn_s_setprio(0);
            hab = nab; hcj = ncj;
        }
    }
    const float2 zero2 = make_float2(0.f, 0.f);
    float2 y1p[8];
#pragma unroll
    for (int q = 0; q < 8; ++q) {
        float2 b2 = *(const float2*)(b0p + 2*q);
        y1p[q] = leaky2(pk_add_vs(acc0p[q], b2));
    }

    // ===== TAGConv layer 1: 16 -> 8, Horner, packed: out = z0+A(z1+A(z2+A z3)) =====
    float2 cur2[4];
    __builtin_amdgcn_s_setprio(1);
#pragma unroll
    for (int q = 0; q < 4; ++q) {
        float2 w0 = *(const float2*)(W1p + 384 + 2*q);
        cur2[q] = pk_mul_blo_s(y1p[0], w0);
        float2 w1 = *(const float2*)(W1p + 384 + 8 + 2*q);
        cur2[q] = pk_fma_bhi_s(y1p[0], w1, cur2[q]);
#pragma unroll
        for (int p8 = 1; p8 < 8; ++p8) {
            float2 wl = *(const float2*)(W1p + 384 + (2*p8)*8 + 2*q);
            float2 wh = *(const float2*)(W1p + 384 + (2*p8+1)*8 + 2*q);
            cur2[q] = pk_fma_blo_s(y1p[p8], wl, cur2[q]);
            cur2[q] = pk_fma_bhi_s(y1p[p8], wh, cur2[q]);
        }
    }
    __builtin_amdgcn_s_setprio(0);
#pragma unroll
    for (int kh = 2; kh >= 0; --kh) {
        *(float4*)(slab + n * 12)     = make_float4(cur2[0].x, cur2[0].y, cur2[1].x, cur2[1].y);
        *(float4*)(slab + n * 12 + 4) = make_float4(cur2[2].x, cur2[2].y, cur2[3].x, cur2[3].y);
        WSYNC();
        float2 ag[4] = {zero2, zero2, zero2, zero2};
#pragma unroll
        for (int m = 0; m < 10; ++m) {
            const float4 p = *(const float4*)(slab + m * 12);
            const float4 r = *(const float4*)(slab + m * 12 + 4);
            const float2 pa = make_float2(p.x, p.y), pb = make_float2(p.z, p.w);
            const float2 ra = make_float2(r.x, r.y), rb = make_float2(r.z, r.w);
            const float2 am = arow2[m >> 1];
            if ((m & 1) == 0) {
                ag[0] = pk_fma_blo(am, pa, ag[0]);
                ag[1] = pk_fma_blo(am, pb, ag[1]);
                ag[2] = pk_fma_blo(am, ra, ag[2]);
                ag[3] = pk_fma_blo(am, rb, ag[3]);
            } else {
                ag[0] = pk_fma_bhi(am, pa, ag[0]);
                ag[1] = pk_fma_bhi(am, pb, ag[1]);
                ag[2] = pk_fma_bhi(am, ra, ag[2]);
                ag[3] = pk_fma_bhi(am, rb, ag[3]);
            }
        }
        WSYNC();
        __builtin_amdgcn_s_setprio(1);
#pragma unroll
        for (int q = 0; q < 4; ++q) {
            cur2[q] = ag[q];
#pragma unroll
            for (int p8 = 0; p8 < 8; ++p8) {
                float2 wl = *(const float2*)(W1p + kh*128 + (2*p8)*8 + 2*q);
                float2 wh = *(const float2*)(W1p + kh*128 + (2*p8+1)*8 + 2*q);
                cur2[q] = pk_fma_blo_s(y1p[p8], wl, cur2[q]);
                cur2[q] = pk_fma_bhi_s(y1p[p8], wh, cur2[q]);
            }
        }
        __builtin_amdgcn_s_setprio(0);
    }
    float2 y2p[4];
#pragma unroll
    for (int q = 0; q < 4; ++q) {
        float2 b2 = *(const float2*)(b1p + 2*q);
        y2p[q] = leaky2(pk_add_vs(cur2[q], b2));
    }

    // ================= heads =================
    *(float4*)(slab + n * 12)     = make_float4(y2p[0].x, y2p[0].y, y2p[1].x, y2p[1].y);
    *(float4*)(slab + n * 12 + 4) = make_float4(y2p[2].x, y2p[2].y, y2p[3].x, y2p[3].y);

    float2 accA = zero2, accT = zero2;
#pragma unroll
    for (int q = 0; q < 4; ++q) {
        float2 bp2 = *(const float2*)(bpp + 2*q);
        float2 cp2 = *(const float2*)(cpp + 2*q);
        accA = pk_fma_vs(y2p[q], bp2, accA);
        accT = pk_fma_vs(y2p[q], cp2, accT);
    }
    const float ay = accA.x + accA.y;
    const float ty = accT.x + accT.y;
    if (valid)
        out[OFF_AIK + (size_t)g * 10 + n] = a0v + fmaxf(ay, 0.f);

    float tk = ty * (1.f - fmaxf(x2, 0.f));
    if (tk == 0.f) tk = -1e10f;
    const float tks = tk * LOG2E;     // exp2-scaled logit (stays live in reg)

    float2 yw2[4];
#pragma unroll
    for (int qd = 0; qd < 4; ++qd) {
        float2 aA = zero2, aB = zero2;
#pragma unroll
        for (int q = 0; q < 4; ++q) {
            float2 wA = *(const float2*)(wwp + (2*qd)*8 + 2*q);
            float2 wB = *(const float2*)(wwp + (2*qd+1)*8 + 2*q);
            aA = pk_fma_vs(y2p[q], wA, aA);
            aB = pk_fma_vs(y2p[q], wB, aB);
        }
        yw2[qd] = make_float2(aA.x + aA.y, aB.x + aB.y);
    }
    WSYNC();   // y2 rows visible
    float kyr[10];   // exp2-scaled logits; stay live across the barrier
#pragma unroll
    for (int m = 0; m < 10; ++m) {
        const float4 p = *(const float4*)(slab + m * 12);
        const float4 r = *(const float4*)(slab + m * 12 + 4);
        float2 acc = pk_mul2(yw2[0], make_float2(p.x, p.y));
        acc = pk_fma2(yw2[1], make_float2(p.z, p.w), acc);
        acc = pk_fma2(yw2[2], make_float2(r.x, r.y), acc);
        acc = pk_fma2(yw2[3], make_float2(r.z, r.w), acc);
        kyr[m] = (acc.x + acc.y) * LOG2E;
    }
    WSYNC();   // all y2 reads done; rows reusable for ky (stride 12, b128-packed)
    *(float4*)(slab + n * 12)     = make_float4(kyr[0], kyr[1], kyr[2], kyr[3]);
    *(float4*)(slab + n * 12 + 4) = make_float4(kyr[4], kyr[5], kyr[6], kyr[7]);
    *(float2*)(slab + n * 12 + 8) = make_float2(kyr[8], kyr[9]);
    slab[120 + n] = tks;

    __syncthreads();   // the ONE cross-wave barrier

    const int ko0 = (w + 1) & 3, ko1 = (w + 2) & 3, ko2 = (w + 3) & 3;

    // ---- t softmax over K: own logit from reg, 3 other-slab reads ----
    {
        const float u0 = sm[(ko0*GPW + s)*SLAB + 120 + n];
        const float u1 = sm[(ko1*GPW + s)*SLAB + 120 + n];
        const float u2 = sm[(ko2*GPW + s)*SLAB + 120 + n];
        const float mx = fmaxf(fmaxf(tks, u0), fmaxf(u1, u2));
        const float eo = fexp2(tks - mx);
        const float den = eo + fexp2(u0 - mx) + fexp2(u1 - mx) + fexp2(u2 - mx);
        if (valid)
            out[OFF_TJ + (size_t)g * 10 + n] = eo * rcpf(den);
    }
    // ---- k_ij softmax over K: own row from kyr regs, 3 other slabs x 3 reads ----
    {
        const float* sA = sm + (ko0*GPW + s)*SLAB + n * 12;
        const float* sB = sm + (ko1*GPW + s)*SLAB + n * 12;
        const float* sC = sm + (ko2*GPW + s)*SLAB + n * 12;
        const float4 a0 = *(const float4*)(sA);
        const float4 a1 = *(const float4*)(sA + 4);
        const float2 a2 = *(const float2*)(sA + 8);
        const float4 b0 = *(const float4*)(sB);
        const float4 b1 = *(const float4*)(sB + 4);
        const float2 b2 = *(const float2*)(sB + 8);
        const float4 c0 = *(const float4*)(sC);
        const float4 c1 = *(const float4*)(sC + 4);
        const float2 c2 = *(const float2*)(sC + 8);
        float va[10], vb[10], vc[10];
        va[0]=a0.x; va[1]=a0.y; va[2]=a0.z; va[3]=a0.w;
        va[4]=a1.x; va[5]=a1.y; va[6]=a1.z; va[7]=a1.w; va[8]=a2.x; va[9]=a2.y;
        vb[0]=b0.x; vb[1]=b0.y; vb[2]=b0.z; vb[3]=b0.w;
        vb[4]=b1.x; vb[5]=b1.y; vb[6]=b1.z; vb[7]=b1.w; vb[8]=b2.x; vb[9]=b2.y;
        vc[0]=c0.x; vc[1]=c0.y; vc[2]=c0.z; vc[3]=c0.w;
        vc[4]=c1.x; vc[5]=c1.y; vc[6]=c1.z; vc[7]=c1.w; vc[8]=c2.x; vc[9]=c2.y;
        float o[10];
#pragma unroll
        for (int m = 0; m < 10; ++m) {
            const float mx = fmaxf(fmaxf(kyr[m], va[m]), fmaxf(vb[m], vc[m]));
            const float eo = fexp2(kyr[m] - mx);
            const float den = eo + fexp2(va[m] - mx) + fexp2(vb[m] - mx) + fexp2(vc[m] - mx);
            o[m] = eo * rcpf(den);
        }
        if (valid) {
            float* po = out + (size_t)g * 100 + n * 10;
#pragma unroll
            for (int q = 0; q < 5; ++q)
                ((float2*)po)[q] = make_float2(o[2*q], o[2*q+1]);
        }
    }
}

extern "C" void kernel_launch(void* const* d_in, const int* in_sizes, int n_in,
                              void* d_out, int out_size, void* d_ws, size_t ws_size,
                              hipStream_t stream) {
    const float* x   = (const float*)d_in[0];
    // d_in[1] = edge_index: deterministic pattern, never read
    const float* ew  = (const float*)d_in[2];
    const float* eig = (const float*)d_in[6];
    const float* a0  = (const float*)d_in[7];
    const float* W0  = (const float*)d_in[8];
    const float* b0  = (const float*)d_in[9];
    const float* W1  = (const float*)d_in[10];
    const float* b1  = (const float*)d_in[11];
    const float* bpw = (const float*)d_in[12];
    const float* cpw = (const float*)d_in[13];
    const float* www = (const float*)d_in[14];
    float* out = (float*)d_out;

    const int grid = (BATCH + GPW - 1) / GPW;   // 5462
    gnn_fused<<<dim3(grid), dim3(NTHREADS), 0, stream>>>(
        x, ew, eig, a0, W0, b0, W1, b1, bpw, cpw, www, out);
}